// Round 3
// baseline (1806.880 us; speedup 1.0000x reference)
//
#include <hip/hip_runtime.h>
#include <hip/hip_bf16.h>
#include <math.h>

#define N_NODES 100000
#define N_EDGES 1600000
#define N_REL   100
#define H       8
#define DH      16
#define D       128
#define DFF     512
#define ALPHA   0.1f

#define NB_SCAN ((N_NODES + 255) / 256)   // 391

typedef unsigned int uint32;

__device__ __forceinline__ float bf2f(ushort u) {
    union { uint32 i; float f; } c; c.i = ((uint32)u) << 16; return c.f;
}
__device__ __forceinline__ ushort f2bf(float f) {
    union { uint32 i; float f; } c; c.f = f;
    uint32 i = c.i;
    uint32 r = (i + 0x7FFFu + ((i >> 16) & 1u)) >> 16;   // RNE
    return (ushort)r;
}
__device__ __forceinline__ uint32 pack2bf(float a, float b) {
    return (uint32)f2bf(a) | ((uint32)f2bf(b) << 16);
}

// ---------------- CSR construction ----------------

__global__ void hist_kernel(const int* __restrict__ dst, int* __restrict__ cnt) {
    int i = blockIdx.x * blockDim.x + threadIdx.x;
    int stride = gridDim.x * blockDim.x;
    for (; i < N_EDGES; i += stride)
        atomicAdd(&cnt[dst[i]], 1);
}

__global__ void scan1_kernel(const int* __restrict__ cnt, int* __restrict__ off,
                             int* __restrict__ bsum) {
    __shared__ int s[256];
    int t = threadIdx.x;
    int i = blockIdx.x * 256 + t;
    int v = (i < N_NODES) ? cnt[i] : 0;
    s[t] = v;
    __syncthreads();
    for (int d = 1; d < 256; d <<= 1) {
        int x = 0;
        if (t >= d) x = s[t - d];
        __syncthreads();
        s[t] += x;
        __syncthreads();
    }
    if (i < N_NODES) off[i] = s[t] - v;      // block-local exclusive
    if (t == 255) bsum[blockIdx.x] = s[255];
}

__global__ void scan2_kernel(const int* __restrict__ bsum, int* __restrict__ bpre) {
    __shared__ int s[512];
    int t = threadIdx.x;
    int v = (t < NB_SCAN) ? bsum[t] : 0;
    s[t] = v;
    __syncthreads();
    for (int d = 1; d < 512; d <<= 1) {
        int x = 0;
        if (t >= d) x = s[t - d];
        __syncthreads();
        s[t] += x;
        __syncthreads();
    }
    if (t < NB_SCAN) bpre[t] = s[t] - v;     // exclusive over block sums
}

__global__ void scan3_kernel(int* __restrict__ off, const int* __restrict__ bpre,
                             int* __restrict__ cursor) {
    int t = threadIdx.x;
    int i = blockIdx.x * 256 + t;
    if (i < N_NODES) {
        int val = off[i] + bpre[blockIdx.x];
        off[i] = val;
        cursor[i] = val;
    }
    if (blockIdx.x == 0 && t == 0) off[N_NODES] = N_EDGES;
}

// pack src (17 bits) | rid (7 bits) << 17
__global__ void fill_kernel(const int* __restrict__ src, const int* __restrict__ dst,
                            const int* __restrict__ rid, int* __restrict__ cursor,
                            int* __restrict__ csr) {
    int i = blockIdx.x * blockDim.x + threadIdx.x;
    int stride = gridDim.x * blockDim.x;
    for (; i < N_EDGES; i += stride) {
        int d = dst[i];
        int p = atomicAdd(&cursor[d], 1);
        csr[p] = src[i] | (rid[i] << 17);
    }
}

// ---------------- LN + matmul (projections), bf16 output ----------------
// block = 256 threads, 32 rows per block. out[r, :] = bf16( LN(X[r, :]) @ W )
__global__ void ln_matmul_kernel(const float* __restrict__ X, const float* __restrict__ g,
                                 const float* __restrict__ b, const float* __restrict__ W,
                                 ushort* __restrict__ outb, int nrows) {
    __shared__ float xn[32][D + 4];
    int t = threadIdx.x;
    int r0 = blockIdx.x * 32;
    {
        int lr = t >> 3;              // local row 0..31
        int sub = t & 7;              // 8 threads per row, 16 elems each
        int row = r0 + lr;
        float x[16];
        float s = 0.f, ss = 0.f;
        if (row < nrows) {
            const float* Xp = X + (size_t)row * D + sub * 16;
            #pragma unroll
            for (int i = 0; i < 4; ++i) {
                float4 x4 = ((const float4*)Xp)[i];
                x[i*4+0] = x4.x; x[i*4+1] = x4.y; x[i*4+2] = x4.z; x[i*4+3] = x4.w;
            }
            #pragma unroll
            for (int i = 0; i < 16; ++i) { s += x[i]; ss += x[i]*x[i]; }
        } else {
            #pragma unroll
            for (int i = 0; i < 16; ++i) x[i] = 0.f;
        }
        s  += __shfl_xor(s, 1);  s  += __shfl_xor(s, 2);  s  += __shfl_xor(s, 4);
        ss += __shfl_xor(ss, 1); ss += __shfl_xor(ss, 2); ss += __shfl_xor(ss, 4);
        float m  = s * (1.f / D);
        float var = ss * (1.f / D) - m * m;
        float rs = rsqrtf(var + 1e-5f);
        #pragma unroll
        for (int i = 0; i < 16; ++i) {
            int idx = sub * 16 + i;
            float yv = (row < nrows) ? ((x[i] - m) * rs * g[idx] + b[idx]) : 0.f;
            xn[lr][idx] = yv;
        }
    }
    __syncthreads();

    int cg = t & 31;   // 32 col groups * 4 cols
    int rg = t >> 5;   // 8 row groups * 4 rows
    float4 acc[4];
    #pragma unroll
    for (int i = 0; i < 4; ++i) acc[i] = make_float4(0.f, 0.f, 0.f, 0.f);
    const float4* Wp = (const float4*)W + cg;
    #pragma unroll 8
    for (int d = 0; d < D; ++d) {
        float4 w = Wp[d * (D / 4)];
        #pragma unroll
        for (int i = 0; i < 4; ++i) {
            float xv = xn[rg * 4 + i][d];
            acc[i].x = fmaf(xv, w.x, acc[i].x);
            acc[i].y = fmaf(xv, w.y, acc[i].y);
            acc[i].z = fmaf(xv, w.z, acc[i].z);
            acc[i].w = fmaf(xv, w.w, acc[i].w);
        }
    }
    #pragma unroll
    for (int i = 0; i < 4; ++i) {
        int row = r0 + rg * 4 + i;
        if (row < nrows) {
            ushort4 u;
            u.x = f2bf(acc[i].x); u.y = f2bf(acc[i].y);
            u.z = f2bf(acc[i].z); u.w = f2bf(acc[i].w);
            *(ushort4*)(outb + (size_t)row * D + cg * 4) = u;
        }
    }
}

// ---------------- edge attention (per-dst softmax, node-local) ----------------
// one wave per node; 8 lanes per head, 2 dims per lane
__global__ void attn_kernel(const ushort* __restrict__ k, const ushort* __restrict__ q,
                            const ushort* __restrict__ relp, const int* __restrict__ off,
                            const int* __restrict__ csr,
                            ushort* __restrict__ ex, float* __restrict__ rdenom) {
    int n = blockIdx.x * 4 + (threadIdx.x >> 6);
    int lane = threadIdx.x & 63;
    int hg = lane >> 3;
    int sub = lane & 7;
    int fo2 = (hg * DH + sub * 2) >> 1;            // index in uint32 (bf16 pairs)
    uint32 qb = ((const uint32*)q)[(size_t)n * 64 + fo2];
    float qx = bf2f((ushort)(qb & 0xFFFF)), qy = bf2f((ushort)(qb >> 16));
    int o0 = off[n], o1 = off[n + 1];
    int deg = o1 - o0;
    float scale = log1pf((float)deg) * 0.25f;      // log1p(in_deg)/sqrt(16)
    float denom = 0.f;
    for (int j = o0; j < o1; ++j) {
        uint32 pk = (uint32)csr[j];
        int s  = pk & 0x1FFFF;
        int ri = pk >> 17;
        uint32 kb = ((const uint32*)k)[(size_t)s * 64 + fo2];
        uint32 rb = ((const uint32*)relp)[(size_t)ri * 64 + fo2];
        float p = bf2f((ushort)(kb & 0xFFFF)) * bf2f((ushort)(rb & 0xFFFF)) * qx
                + bf2f((ushort)(kb >> 16))    * bf2f((ushort)(rb >> 16))    * qy;
        p += __shfl_xor(p, 1);
        p += __shfl_xor(p, 2);
        p += __shfl_xor(p, 4);
        float e = __expf(p * scale);
        denom += e;
        if (sub == 0) ex[(size_t)j * H + hg] = f2bf(e);
    }
    if (sub == 0) rdenom[n * H + hg] = (deg > 0) ? (1.f - ALPHA) / denom : 0.f;
}

// ---------------- one diffusion hop (bf16 feat) ----------------
__global__ void diff_kernel(const ushort* __restrict__ fin, ushort* __restrict__ fout,
                            const ushort* __restrict__ f0, const ushort* __restrict__ ex,
                            const float* __restrict__ rdenom, const int* __restrict__ off,
                            const int* __restrict__ csr) {
    int n = blockIdx.x * 4 + (threadIdx.x >> 6);
    int lane = threadIdx.x & 63;
    int hg = lane >> 3;
    int sub = lane & 7;
    int fo2 = (hg * DH + sub * 2) >> 1;
    int o0 = off[n], o1 = off[n + 1];
    float ax = 0.f, ay = 0.f;
    for (int j = o0; j < o1; ++j) {
        int s = csr[j] & 0x1FFFF;
        float a = bf2f(ex[(size_t)j * H + hg]);
        uint32 fb = ((const uint32*)fin)[(size_t)s * 64 + fo2];
        ax = fmaf(a, bf2f((ushort)(fb & 0xFFFF)), ax);
        ay = fmaf(a, bf2f((ushort)(fb >> 16)), ay);
    }
    float rd = rdenom[n * H + hg];                 // (1-alpha)/denom, 0 if deg==0
    uint32 f0b = ((const uint32*)f0)[(size_t)n * 64 + fo2];
    float ox = fmaf(rd, ax, ALPHA * bf2f((ushort)(f0b & 0xFFFF)));
    float oy = fmaf(rd, ay, ALPHA * bf2f((ushort)(f0b >> 16)));
    ((uint32*)fout)[(size_t)n * 64 + fo2] = pack2bf(ox, oy);
}

// ---------------- fused residual + LN + FFN + residual ----------------
// out = relu(LN(feat+ent) @ W1 + b1) @ W2 + b2 + (feat+ent);  feat is bf16
__global__ void ffn_kernel(const ushort* __restrict__ featb, const float* __restrict__ ent,
                           const float* __restrict__ gff, const float* __restrict__ bff,
                           const float* __restrict__ W1, const float* __restrict__ b1,
                           const float* __restrict__ W2, const float* __restrict__ b2,
                           float* __restrict__ out) {
    __shared__ float y[32][D + 4];
    __shared__ float hs[32][D + 4];
    int t = threadIdx.x;
    int r0 = blockIdx.x * 32;
    {
        int lr = t >> 3, sub = t & 7;
        int row = r0 + lr;
        const ushort* fp = featb + (size_t)row * D + sub * 16;
        const float*  ep = ent   + (size_t)row * D + sub * 16;
        uint4 fa = ((const uint4*)fp)[0];
        uint4 fb = ((const uint4*)fp)[1];
        uint32 fw[8] = {fa.x, fa.y, fa.z, fa.w, fb.x, fb.y, fb.z, fb.w};
        float x[16];
        #pragma unroll
        for (int i = 0; i < 8; ++i) {
            x[2*i]   = bf2f((ushort)(fw[i] & 0xFFFF));
            x[2*i+1] = bf2f((ushort)(fw[i] >> 16));
        }
        #pragma unroll
        for (int i = 0; i < 4; ++i) {
            float4 e4 = ((const float4*)ep)[i];
            x[4*i]   += e4.x; x[4*i+1] += e4.y;
            x[4*i+2] += e4.z; x[4*i+3] += e4.w;
        }
        float s = 0.f, ss = 0.f;
        #pragma unroll
        for (int i = 0; i < 16; ++i) { s += x[i]; ss += x[i]*x[i]; }
        s  += __shfl_xor(s, 1);  s  += __shfl_xor(s, 2);  s  += __shfl_xor(s, 4);
        ss += __shfl_xor(ss, 1); ss += __shfl_xor(ss, 2); ss += __shfl_xor(ss, 4);
        float m  = s * (1.f / D);
        float var = ss * (1.f / D) - m * m;
        float rs = rsqrtf(var + 1e-5f);
        #pragma unroll
        for (int i = 0; i < 16; ++i) {
            int idx = sub * 16 + i;
            y[lr][idx] = (x[i] - m) * rs * gff[idx] + bff[idx];
        }
    }
    __syncthreads();

    int cg = t & 31;
    int rg = t >> 5;
    float4 oacc[4];
    #pragma unroll
    for (int i = 0; i < 4; ++i) oacc[i] = make_float4(0.f, 0.f, 0.f, 0.f);

    for (int c = 0; c < 4; ++c) {
        // GEMM1 chunk: h = relu(y @ W1[:, c*128:(c+1)*128] + b1)
        float4 ha[4];
        float4 b1v = *(const float4*)(b1 + c * 128 + cg * 4);
        #pragma unroll
        for (int i = 0; i < 4; ++i) ha[i] = b1v;
        const float4* W1p = (const float4*)W1 + c * 32 + cg;
        #pragma unroll 8
        for (int d = 0; d < D; ++d) {
            float4 w = W1p[d * (DFF / 4)];
            #pragma unroll
            for (int i = 0; i < 4; ++i) {
                float xv = y[rg * 4 + i][d];
                ha[i].x = fmaf(xv, w.x, ha[i].x);
                ha[i].y = fmaf(xv, w.y, ha[i].y);
                ha[i].z = fmaf(xv, w.z, ha[i].z);
                ha[i].w = fmaf(xv, w.w, ha[i].w);
            }
        }
        __syncthreads();   // previous chunk's GEMM2 reads of hs are done
        #pragma unroll
        for (int i = 0; i < 4; ++i) {
            float4 r;
            r.x = fmaxf(ha[i].x, 0.f); r.y = fmaxf(ha[i].y, 0.f);
            r.z = fmaxf(ha[i].z, 0.f); r.w = fmaxf(ha[i].w, 0.f);
            *(float4*)&hs[rg * 4 + i][cg * 4] = r;
        }
        __syncthreads();
        // GEMM2 partial: oacc += h_chunk @ W2[c*128:(c+1)*128, :]
        const float4* W2p = (const float4*)W2 + (size_t)(c * 128) * 32 + cg;
        #pragma unroll 8
        for (int fc = 0; fc < 128; ++fc) {
            float4 w = W2p[(size_t)fc * 32];
            #pragma unroll
            for (int i = 0; i < 4; ++i) {
                float xv = hs[rg * 4 + i][fc];
                oacc[i].x = fmaf(xv, w.x, oacc[i].x);
                oacc[i].y = fmaf(xv, w.y, oacc[i].y);
                oacc[i].z = fmaf(xv, w.z, oacc[i].z);
                oacc[i].w = fmaf(xv, w.w, oacc[i].w);
            }
        }
    }

    float4 b2v = *(const float4*)(b2 + cg * 4);
    #pragma unroll
    for (int i = 0; i < 4; ++i) {
        int row = r0 + rg * 4 + i;
        uint2 fr = *(const uint2*)(featb + (size_t)row * D + cg * 4);
        float4 ev = *(const float4*)(ent + (size_t)row * D + cg * 4);
        float f0 = bf2f((ushort)(fr.x & 0xFFFF));
        float f1 = bf2f((ushort)(fr.x >> 16));
        float f2 = bf2f((ushort)(fr.y & 0xFFFF));
        float f3 = bf2f((ushort)(fr.y >> 16));
        float4 r;
        r.x = oacc[i].x + b2v.x + f0 + ev.x;
        r.y = oacc[i].y + b2v.y + f1 + ev.y;
        r.z = oacc[i].z + b2v.z + f2 + ev.z;
        r.w = oacc[i].w + b2v.w + f3 + ev.w;
        *(float4*)(out + (size_t)row * D + cg * 4) = r;
    }
}

extern "C" void kernel_launch(void* const* d_in, const int* in_sizes, int n_in,
                              void* d_out, int out_size, void* d_ws, size_t ws_size,
                              hipStream_t stream) {
    const float* ent   = (const float*)d_in[0];
    const float* relf  = (const float*)d_in[1];
    const float* Wh    = (const float*)d_in[2];
    const float* Wt    = (const float*)d_in[3];
    const float* We    = (const float*)d_in[4];
    const float* Wr    = (const float*)d_in[5];
    const float* g_ent = (const float*)d_in[6];
    const float* b_ent = (const float*)d_in[7];
    const float* g_rel = (const float*)d_in[8];
    const float* b_rel = (const float*)d_in[9];
    const float* g_ff  = (const float*)d_in[10];
    const float* b_ff  = (const float*)d_in[11];
    const float* W1    = (const float*)d_in[12];
    const float* b1    = (const float*)d_in[13];
    const float* W2    = (const float*)d_in[14];
    const float* b2    = (const float*)d_in[15];
    const int*   src   = (const int*)d_in[16];
    const int*   dst   = (const int*)d_in[17];
    const int*   rid   = (const int*)d_in[18];
    float* out = (float*)d_out;

    // ---- d_out doubles as scratch until the final ffn_kernel ----
    // ex:   N_EDGES*H bf16 = 25.6 MB   (dead after last diff)
    // vbuf: N_NODES*D bf16 = 25.6 MB   (feat0; dead after last diff)
    // total exactly 51.2 MB = out_size*4
    ushort* ex   = (ushort*)d_out;
    ushort* vbuf = (ushort*)((char*)d_out + (size_t)N_EDGES * H * 2);

    // ---- workspace layout (~61 MB total) ----
    char* w = (char*)d_ws;
    auto alloc = [&](size_t bytes) { char* p = w; w += (bytes + 255) & ~(size_t)255; return p; };
    ushort* kbuf = (ushort*)alloc((size_t)N_NODES * D * 2);   // bf16; reused as feat ping A
    ushort* qbuf = (ushort*)alloc((size_t)N_NODES * D * 2);   // bf16; reused as feat ping B
    ushort* relp = (ushort*)alloc((size_t)N_REL * D * 2);
    int*   off   = (int*)alloc((size_t)(N_NODES + 1) * 4);
    float* rden  = (float*)alloc((size_t)N_NODES * H * 4);    // also cnt/cursor (dead before rden written)
    int*   cnt   = (int*)rden;
    int*   csr   = (int*)alloc((size_t)N_EDGES * 4);          // src | rid<<17
    int*   bsum  = (int*)alloc((size_t)NB_SCAN * 4);
    int*   bpre  = (int*)alloc((size_t)NB_SCAN * 4);

    hipMemsetAsync(cnt, 0, (size_t)N_NODES * 4, stream);
    hist_kernel<<<1024, 256, 0, stream>>>(dst, cnt);
    scan1_kernel<<<NB_SCAN, 256, 0, stream>>>(cnt, off, bsum);
    scan2_kernel<<<1, 512, 0, stream>>>(bsum, bpre);
    scan3_kernel<<<NB_SCAN, 256, 0, stream>>>(off, bpre, cnt);
    fill_kernel<<<1024, 256, 0, stream>>>(src, dst, rid, cnt, csr);

    ln_matmul_kernel<<<3125, 256, 0, stream>>>(ent, g_ent, b_ent, Wh, kbuf, N_NODES);
    ln_matmul_kernel<<<3125, 256, 0, stream>>>(ent, g_ent, b_ent, Wt, qbuf, N_NODES);
    ln_matmul_kernel<<<3125, 256, 0, stream>>>(ent, g_ent, b_ent, We, vbuf, N_NODES);
    ln_matmul_kernel<<<4,    256, 0, stream>>>(relf, g_rel, b_rel, Wr, relp, N_REL);

    attn_kernel<<<25000, 256, 0, stream>>>(kbuf, qbuf, relp, off, csr, ex, rden);

    diff_kernel<<<25000, 256, 0, stream>>>(vbuf, kbuf, vbuf, ex, rden, off, csr);
    diff_kernel<<<25000, 256, 0, stream>>>(kbuf, qbuf, vbuf, ex, rden, off, csr);
    diff_kernel<<<25000, 256, 0, stream>>>(qbuf, kbuf, vbuf, ex, rden, off, csr);
    diff_kernel<<<25000, 256, 0, stream>>>(kbuf, qbuf, vbuf, ex, rden, off, csr);

    ffn_kernel<<<3125, 256, 0, stream>>>(qbuf, ent, g_ff, b_ff, W1, b1, W2, b2, out);
}

// Round 5
// 1339.325 us; speedup vs baseline: 1.3491x; 1.3491x over previous
//
#include <hip/hip_runtime.h>
#include <hip/hip_bf16.h>
#include <math.h>

#define N_NODES 100000
#define N_EDGES 1600000
#define N_REL   100
#define H       8
#define DH      16
#define D       128
#define DFF     512
#define ALPHA   0.1f

#define NB_SCAN ((N_NODES + 255) / 256)   // 391

typedef unsigned int uint32;

using f32x4 = __attribute__((ext_vector_type(4))) float;
using s16x8 = __attribute__((ext_vector_type(8))) short;
using s16x4 = __attribute__((ext_vector_type(4))) short;

__device__ __forceinline__ float bf2f(ushort u) {
    union { uint32 i; float f; } c; c.i = ((uint32)u) << 16; return c.f;
}
__device__ __forceinline__ ushort f2bf(float f) {
    union { uint32 i; float f; } c; c.f = f;
    uint32 i = c.i;
    uint32 r = (i + 0x7FFFu + ((i >> 16) & 1u)) >> 16;   // RNE
    return (ushort)r;
}
__device__ __forceinline__ uint32 pack2bf(float a, float b) {
    return (uint32)f2bf(a) | ((uint32)f2bf(b) << 16);
}

// ---------------- CSR construction ----------------

__global__ void hist_kernel(const int* __restrict__ dst, int* __restrict__ cnt) {
    int i = blockIdx.x * blockDim.x + threadIdx.x;
    int stride = gridDim.x * blockDim.x;
    for (; i < N_EDGES; i += stride)
        atomicAdd(&cnt[dst[i]], 1);
}

__global__ void scan1_kernel(const int* __restrict__ cnt, int* __restrict__ off,
                             int* __restrict__ bsum) {
    __shared__ int s[256];
    int t = threadIdx.x;
    int i = blockIdx.x * 256 + t;
    int v = (i < N_NODES) ? cnt[i] : 0;
    s[t] = v;
    __syncthreads();
    for (int d = 1; d < 256; d <<= 1) {
        int x = 0;
        if (t >= d) x = s[t - d];
        __syncthreads();
        s[t] += x;
        __syncthreads();
    }
    if (i < N_NODES) off[i] = s[t] - v;      // block-local exclusive
    if (t == 255) bsum[blockIdx.x] = s[255];
}

__global__ void scan2_kernel(const int* __restrict__ bsum, int* __restrict__ bpre) {
    __shared__ int s[512];
    int t = threadIdx.x;
    int v = (t < NB_SCAN) ? bsum[t] : 0;
    s[t] = v;
    __syncthreads();
    for (int d = 1; d < 512; d <<= 1) {
        int x = 0;
        if (t >= d) x = s[t - d];
        __syncthreads();
        s[t] += x;
        __syncthreads();
    }
    if (t < NB_SCAN) bpre[t] = s[t] - v;     // exclusive over block sums
}

__global__ void scan3_kernel(int* __restrict__ off, const int* __restrict__ bpre,
                             int* __restrict__ cursor) {
    int t = threadIdx.x;
    int i = blockIdx.x * 256 + t;
    if (i < N_NODES) {
        int val = off[i] + bpre[blockIdx.x];
        off[i] = val;
        cursor[i] = val;
    }
    if (blockIdx.x == 0 && t == 0) off[N_NODES] = N_EDGES;
}

// pack src (17 bits) | rid (7 bits) << 17
__global__ void fill_kernel(const int* __restrict__ src, const int* __restrict__ dst,
                            const int* __restrict__ rid, int* __restrict__ cursor,
                            int* __restrict__ csr) {
    int i = blockIdx.x * blockDim.x + threadIdx.x;
    int stride = gridDim.x * blockDim.x;
    for (; i < N_EDGES; i += stride) {
        int d = dst[i];
        int p = atomicAdd(&cursor[d], 1);
        csr[p] = src[i] | (rid[i] << 17);
    }
}

// ---------------- weight prep: pack into MFMA fragment layouts (bf16) ----------------
// w1p: A-frag layout of W1^T for 16x16x32 (GEMM1 swapped).  idx = ch<<11 | f<<8 | kt<<6 | lane
__global__ void prep_w1_kernel(const float* __restrict__ W1, uint4* __restrict__ w1p) {
    int idx = blockIdx.x * 256 + threadIdx.x;          // 8192 total
    int lane = idx & 63, kt = (idx >> 6) & 3, f = (idx >> 8) & 7, ch = idx >> 11;
    int ff = ch * 128 + f * 16 + (lane & 15);
    int k0 = kt * 32 + (lane >> 4) * 8;
    uint4 u;
    u.x = pack2bf(W1[(size_t)(k0 + 0) * DFF + ff], W1[(size_t)(k0 + 1) * DFF + ff]);
    u.y = pack2bf(W1[(size_t)(k0 + 2) * DFF + ff], W1[(size_t)(k0 + 3) * DFF + ff]);
    u.z = pack2bf(W1[(size_t)(k0 + 4) * DFF + ff], W1[(size_t)(k0 + 5) * DFF + ff]);
    u.w = pack2bf(W1[(size_t)(k0 + 6) * DFF + ff], W1[(size_t)(k0 + 7) * DFF + ff]);
    w1p[idx] = u;
}

// w2p: B-frag layout of W2 for 16x16x16 (GEMM2).  idx = ch<<12 | f<<9 | o<<6 | lane
__global__ void prep_w2_kernel(const float* __restrict__ W2, uint2* __restrict__ w2p) {
    int idx = blockIdx.x * 256 + threadIdx.x;          // 16384 total
    int lane = idx & 63, o = (idx >> 6) & 7, f = (idx >> 9) & 7, ch = idx >> 12;
    int col = o * 16 + (lane & 15);
    int k0 = ch * 128 + f * 16 + (lane >> 4) * 4;
    uint2 u;
    u.x = pack2bf(W2[(size_t)(k0 + 0) * D + col], W2[(size_t)(k0 + 1) * D + col]);
    u.y = pack2bf(W2[(size_t)(k0 + 2) * D + col], W2[(size_t)(k0 + 3) * D + col]);
    w2p[idx] = u;
}

// wp: B-frag layout of a [128][128] proj weight for 16x16x32. idx = kt<<9 | o<<6 | lane
__global__ void prep_wp_kernel(const float* __restrict__ W, uint4* __restrict__ wp) {
    int idx = blockIdx.x * 256 + threadIdx.x;          // 2048 total
    int lane = idx & 63, o = (idx >> 6) & 7, kt = idx >> 9;
    int col = o * 16 + (lane & 15);
    int k0 = kt * 32 + (lane >> 4) * 8;
    uint4 u;
    u.x = pack2bf(W[(size_t)(k0 + 0) * D + col], W[(size_t)(k0 + 1) * D + col]);
    u.y = pack2bf(W[(size_t)(k0 + 2) * D + col], W[(size_t)(k0 + 3) * D + col]);
    u.z = pack2bf(W[(size_t)(k0 + 4) * D + col], W[(size_t)(k0 + 5) * D + col]);
    u.w = pack2bf(W[(size_t)(k0 + 6) * D + col], W[(size_t)(k0 + 7) * D + col]);
    wp[idx] = u;
}

// ---------------- LN + matmul scalar (kept for rel, 100 rows) ----------------
__global__ void ln_matmul_kernel(const float* __restrict__ X, const float* __restrict__ g,
                                 const float* __restrict__ b, const float* __restrict__ W,
                                 ushort* __restrict__ outb, int nrows) {
    __shared__ float xn[32][D + 4];
    int t = threadIdx.x;
    int r0 = blockIdx.x * 32;
    {
        int lr = t >> 3, sub = t & 7;
        int row = r0 + lr;
        float x[16];
        float s = 0.f, ss = 0.f;
        if (row < nrows) {
            const float* Xp = X + (size_t)row * D + sub * 16;
            #pragma unroll
            for (int i = 0; i < 4; ++i) {
                float4 x4 = ((const float4*)Xp)[i];
                x[i*4+0] = x4.x; x[i*4+1] = x4.y; x[i*4+2] = x4.z; x[i*4+3] = x4.w;
            }
            #pragma unroll
            for (int i = 0; i < 16; ++i) { s += x[i]; ss += x[i]*x[i]; }
        } else {
            #pragma unroll
            for (int i = 0; i < 16; ++i) x[i] = 0.f;
        }
        s  += __shfl_xor(s, 1);  s  += __shfl_xor(s, 2);  s  += __shfl_xor(s, 4);
        ss += __shfl_xor(ss, 1); ss += __shfl_xor(ss, 2); ss += __shfl_xor(ss, 4);
        float m  = s * (1.f / D);
        float var = ss * (1.f / D) - m * m;
        float rs = rsqrtf(var + 1e-5f);
        #pragma unroll
        for (int i = 0; i < 16; ++i) {
            int idx = sub * 16 + i;
            float yv = (row < nrows) ? ((x[i] - m) * rs * g[idx] + b[idx]) : 0.f;
            xn[lr][idx] = yv;
        }
    }
    __syncthreads();

    int cg = t & 31;
    int rg = t >> 5;
    float4 acc[4];
    #pragma unroll
    for (int i = 0; i < 4; ++i) acc[i] = make_float4(0.f, 0.f, 0.f, 0.f);
    const float4* Wp = (const float4*)W + cg;
    #pragma unroll 8
    for (int d = 0; d < D; ++d) {
        float4 w = Wp[d * (D / 4)];
        #pragma unroll
        for (int i = 0; i < 4; ++i) {
            float xv = xn[rg * 4 + i][d];
            acc[i].x = fmaf(xv, w.x, acc[i].x);
            acc[i].y = fmaf(xv, w.y, acc[i].y);
            acc[i].z = fmaf(xv, w.z, acc[i].z);
            acc[i].w = fmaf(xv, w.w, acc[i].w);
        }
    }
    #pragma unroll
    for (int i = 0; i < 4; ++i) {
        int row = r0 + rg * 4 + i;
        if (row < nrows) {
            ushort4 u;
            u.x = f2bf(acc[i].x); u.y = f2bf(acc[i].y);
            u.z = f2bf(acc[i].z); u.w = f2bf(acc[i].w);
            *(ushort4*)(outb + (size_t)row * D + cg * 4) = u;
        }
    }
}

// ---------------- fused LN + 3 projections via MFMA ----------------
// block = 256 = 4 waves; wave handles 16 rows. Lane l: row = base + (l&15),
// holds k-slices (l>>4)*8 + kt*32 + j (j=0..7) -> exactly the 16x16x32 A-frag.
__global__ __launch_bounds__(256) void proj_kernel(
        const float* __restrict__ X, const float* __restrict__ g, const float* __restrict__ b,
        const uint4* __restrict__ whp, const uint4* __restrict__ wtp, const uint4* __restrict__ wep,
        ushort* __restrict__ kout, ushort* __restrict__ qout, ushort* __restrict__ vout) {
    int t = threadIdx.x, wid = t >> 6, l = t & 63, g4 = l >> 4, c = l & 15;
    int rbase = blockIdx.x * 64 + wid * 16;
    int row = rbase + c;
    int rowc = row < N_NODES ? row : N_NODES - 1;
    const float* Xp = X + (size_t)rowc * D;
    float x[32];
    float s = 0.f, ss = 0.f;
    #pragma unroll
    for (int kt = 0; kt < 4; ++kt) {
        float4 a0 = *(const float4*)(Xp + kt * 32 + g4 * 8);
        float4 a1 = *(const float4*)(Xp + kt * 32 + g4 * 8 + 4);
        x[kt*8+0] = a0.x; x[kt*8+1] = a0.y; x[kt*8+2] = a0.z; x[kt*8+3] = a0.w;
        x[kt*8+4] = a1.x; x[kt*8+5] = a1.y; x[kt*8+6] = a1.z; x[kt*8+7] = a1.w;
    }
    #pragma unroll
    for (int i = 0; i < 32; ++i) { s += x[i]; ss += x[i]*x[i]; }
    s  += __shfl_xor(s, 16);  s  += __shfl_xor(s, 32);
    ss += __shfl_xor(ss, 16); ss += __shfl_xor(ss, 32);
    float m  = s * (1.f / D);
    float var = ss * (1.f / D) - m * m;
    float rs = rsqrtf(var + 1e-5f);
    s16x8 yf[4];
    #pragma unroll
    for (int kt = 0; kt < 4; ++kt)
        #pragma unroll
        for (int j = 0; j < 8; ++j) {
            int idx = kt * 32 + g4 * 8 + j;
            yf[kt][j] = (short)f2bf((x[kt*8+j] - m) * rs * g[idx] + b[idx]);
        }

    const uint4* wps[3] = {whp, wtp, wep};
    ushort*      ops[3] = {kout, qout, vout};
    #pragma unroll
    for (int w = 0; w < 3; ++w) {
        f32x4 acc[8];
        #pragma unroll
        for (int o = 0; o < 8; ++o) acc[o] = (f32x4){0.f, 0.f, 0.f, 0.f};
        #pragma unroll
        for (int kt = 0; kt < 4; ++kt)
            #pragma unroll
            for (int o = 0; o < 8; ++o) {
                union { uint4 u; s16x8 v; } cv;
                cv.u = wps[w][(kt * 8 + o) * 64 + l];
                acc[o] = __builtin_amdgcn_mfma_f32_16x16x32_bf16(yf[kt], cv.v, acc[o], 0, 0, 0);
            }
        #pragma unroll
        for (int o = 0; o < 8; ++o)
            #pragma unroll
            for (int r = 0; r < 4; ++r) {
                int orow = rbase + g4 * 4 + r;
                if (orow < N_NODES)
                    ops[w][(size_t)orow * D + o * 16 + c] = f2bf(acc[o][r]);
            }
    }
}

// ---------------- edge attention (per-dst softmax, node-local) ----------------
__global__ void attn_kernel(const ushort* __restrict__ k, const ushort* __restrict__ q,
                            const ushort* __restrict__ relp, const int* __restrict__ off,
                            const int* __restrict__ csr,
                            ushort* __restrict__ ex, float* __restrict__ rdenom) {
    int n = blockIdx.x * 4 + (threadIdx.x >> 6);
    int lane = threadIdx.x & 63;
    int hg = lane >> 3;
    int sub = lane & 7;
    int fo2 = (hg * DH + sub * 2) >> 1;
    uint32 qb = ((const uint32*)q)[(size_t)n * 64 + fo2];
    float qx = bf2f((ushort)(qb & 0xFFFF)), qy = bf2f((ushort)(qb >> 16));
    int o0 = off[n], o1 = off[n + 1];
    int deg = o1 - o0;
    float scale = log1pf((float)deg) * 0.25f;
    float denom = 0.f;
    for (int j = o0; j < o1; ++j) {
        uint32 pk = (uint32)csr[j];
        int s  = pk & 0x1FFFF;
        int ri = pk >> 17;
        uint32 kb = ((const uint32*)k)[(size_t)s * 64 + fo2];
        uint32 rb = ((const uint32*)relp)[(size_t)ri * 64 + fo2];
        float p = bf2f((ushort)(kb & 0xFFFF)) * bf2f((ushort)(rb & 0xFFFF)) * qx
                + bf2f((ushort)(kb >> 16))    * bf2f((ushort)(rb >> 16))    * qy;
        p += __shfl_xor(p, 1);
        p += __shfl_xor(p, 2);
        p += __shfl_xor(p, 4);
        float e = __expf(p * scale);
        denom += e;
        if (sub == 0) ex[(size_t)j * H + hg] = f2bf(e);
    }
    if (sub == 0) rdenom[n * H + hg] = (deg > 0) ? (1.f - ALPHA) / denom : 0.f;
}

// ---------------- one diffusion hop (bf16 feat) ----------------
__global__ void diff_kernel(const ushort* __restrict__ fin, ushort* __restrict__ fout,
                            const ushort* __restrict__ f0, const ushort* __restrict__ ex,
                            const float* __restrict__ rdenom, const int* __restrict__ off,
                            const int* __restrict__ csr) {
    int n = blockIdx.x * 4 + (threadIdx.x >> 6);
    int lane = threadIdx.x & 63;
    int hg = lane >> 3;
    int sub = lane & 7;
    int fo2 = (hg * DH + sub * 2) >> 1;
    int o0 = off[n], o1 = off[n + 1];
    float ax = 0.f, ay = 0.f;
    for (int j = o0; j < o1; ++j) {
        int s = csr[j] & 0x1FFFF;
        float a = bf2f(ex[(size_t)j * H + hg]);
        uint32 fb = ((const uint32*)fin)[(size_t)s * 64 + fo2];
        ax = fmaf(a, bf2f((ushort)(fb & 0xFFFF)), ax);
        ay = fmaf(a, bf2f((ushort)(fb >> 16)), ay);
    }
    float rd = rdenom[n * H + hg];
    uint32 f0b = ((const uint32*)f0)[(size_t)n * 64 + fo2];
    float ox = fmaf(rd, ax, ALPHA * bf2f((ushort)(f0b & 0xFFFF)));
    float oy = fmaf(rd, ay, ALPHA * bf2f((ushort)(f0b >> 16)));
    ((uint32*)fout)[(size_t)n * 64 + fo2] = pack2bf(ox, oy);
}

// ---------------- fused residual + LN + FFN + residual via MFMA ----------------
// GEMM1 swapped: h^T tile = mfma_16x16x32(W1T-frag, y-frag)  ->  lane holds
// h[row=l&15][ff=(l>>4)*4+r], which IS the 16x16x16 A-frag for GEMM2.
__global__ __launch_bounds__(256) void ffn_mfma_kernel(
        const ushort* __restrict__ featb, const float* __restrict__ ent,
        const float* __restrict__ gff, const float* __restrict__ bff,
        const uint4* __restrict__ w1p, const uint2* __restrict__ w2p,
        const float* __restrict__ b1, const float* __restrict__ b2,
        float* __restrict__ out) {
    int t = threadIdx.x, wid = t >> 6, l = t & 63, g4 = l >> 4, c = l & 15;
    int rbase = blockIdx.x * 64 + wid * 16;
    int row = rbase + c;
    int rowc = row < N_NODES ? row : N_NODES - 1;
    const ushort* fp = featb + (size_t)rowc * D;
    const float*  ep = ent   + (size_t)rowc * D;
    float x[32];
    float s = 0.f, ss = 0.f;
    #pragma unroll
    for (int kt = 0; kt < 4; ++kt) {
        uint4  fu = *(const uint4*)(fp + kt * 32 + g4 * 8);
        float4 e0 = *(const float4*)(ep + kt * 32 + g4 * 8);
        float4 e1 = *(const float4*)(ep + kt * 32 + g4 * 8 + 4);
        uint32 fw[4] = {fu.x, fu.y, fu.z, fu.w};
        float  ev[8] = {e0.x, e0.y, e0.z, e0.w, e1.x, e1.y, e1.z, e1.w};
        #pragma unroll
        for (int p = 0; p < 4; ++p) {
            x[kt*8 + 2*p]   = bf2f((ushort)(fw[p] & 0xFFFF)) + ev[2*p];
            x[kt*8 + 2*p+1] = bf2f((ushort)(fw[p] >> 16))    + ev[2*p+1];
        }
    }
    #pragma unroll
    for (int i = 0; i < 32; ++i) { s += x[i]; ss += x[i]*x[i]; }
    s  += __shfl_xor(s, 16);  s  += __shfl_xor(s, 32);
    ss += __shfl_xor(ss, 16); ss += __shfl_xor(ss, 32);
    float m  = s * (1.f / D);
    float var = ss * (1.f / D) - m * m;
    float rs = rsqrtf(var + 1e-5f);
    s16x8 yf[4];
    #pragma unroll
    for (int kt = 0; kt < 4; ++kt)
        #pragma unroll
        for (int j = 0; j < 8; ++j) {
            int idx = kt * 32 + g4 * 8 + j;
            yf[kt][j] = (short)f2bf((x[kt*8+j] - m) * rs * gff[idx] + bff[idx]);
        }

    f32x4 oacc[8];
    #pragma unroll
    for (int o = 0; o < 8; ++o) oacc[o] = (f32x4){0.f, 0.f, 0.f, 0.f};
    const f32x4* b1v4 = (const f32x4*)b1;

    #pragma unroll
    for (int ch = 0; ch < 4; ++ch) {
        // GEMM1 (swapped): h^T[ff][row], init with b1 broadcast over rows
        f32x4 hacc[8];
        #pragma unroll
        for (int f = 0; f < 8; ++f) hacc[f] = b1v4[ch * 32 + f * 4 + g4];
        #pragma unroll
        for (int f = 0; f < 8; ++f)
            #pragma unroll
            for (int kt = 0; kt < 4; ++kt) {
                union { uint4 u; s16x8 v; } cv;
                cv.u = w1p[((ch * 8 + f) * 4 + kt) * 64 + l];
                hacc[f] = __builtin_amdgcn_mfma_f32_16x16x32_bf16(cv.v, yf[kt], hacc[f], 0, 0, 0);
            }
        // relu + pack -> GEMM2 A-frags (k-local = (l>>4)*4 + r)
        s16x4 a2[8];
        #pragma unroll
        for (int f = 0; f < 8; ++f)
            #pragma unroll
            for (int r = 0; r < 4; ++r)
                a2[f][r] = (short)f2bf(fmaxf(hacc[f][r], 0.f));
        // GEMM2: out += h_chunk @ W2_chunk
        #pragma unroll
        for (int o = 0; o < 8; ++o)
            #pragma unroll
            for (int f = 0; f < 8; ++f) {
                union { uint2 u; s16x4 v; } cw;
                cw.u = w2p[((ch * 8 + f) * 8 + o) * 64 + l];
                oacc[o] = __builtin_amdgcn_mfma_f32_16x16x16bf16_1k(a2[f], cw.v, oacc[o], 0, 0, 0);
            }
    }

    // epilogue: + b2 + (feat + ent) residual
    #pragma unroll
    for (int o = 0; o < 8; ++o) {
        int col = o * 16 + c;
        float b2v = b2[col];
        #pragma unroll
        for (int r = 0; r < 4; ++r) {
            int orow = rbase + g4 * 4 + r;
            if (orow < N_NODES) {
                float res = bf2f(featb[(size_t)orow * D + col]) + ent[(size_t)orow * D + col];
                out[(size_t)orow * D + col] = oacc[o][r] + b2v + res;
            }
        }
    }
}

extern "C" void kernel_launch(void* const* d_in, const int* in_sizes, int n_in,
                              void* d_out, int out_size, void* d_ws, size_t ws_size,
                              hipStream_t stream) {
    const float* ent   = (const float*)d_in[0];
    const float* relf  = (const float*)d_in[1];
    const float* Wh    = (const float*)d_in[2];
    const float* Wt    = (const float*)d_in[3];
    const float* We    = (const float*)d_in[4];
    const float* Wr    = (const float*)d_in[5];
    const float* g_ent = (const float*)d_in[6];
    const float* b_ent = (const float*)d_in[7];
    const float* g_rel = (const float*)d_in[8];
    const float* b_rel = (const float*)d_in[9];
    const float* g_ff  = (const float*)d_in[10];
    const float* b_ff  = (const float*)d_in[11];
    const float* W1    = (const float*)d_in[12];
    const float* b1    = (const float*)d_in[13];
    const float* W2    = (const float*)d_in[14];
    const float* b2    = (const float*)d_in[15];
    const int*   src   = (const int*)d_in[16];
    const int*   dst   = (const int*)d_in[17];
    const int*   rid   = (const int*)d_in[18];
    float* out = (float*)d_out;

    // ---- d_out doubles as scratch until the final ffn kernel ----
    ushort* ex   = (ushort*)d_out;                                    // 25.6 MB
    ushort* vbuf = (ushort*)((char*)d_out + (size_t)N_EDGES * H * 2); // 25.6 MB

    // ---- workspace (~62 MB) ----
    char* w = (char*)d_ws;
    auto alloc = [&](size_t bytes) { char* p = w; w += (bytes + 255) & ~(size_t)255; return p; };
    ushort* kbuf = (ushort*)alloc((size_t)N_NODES * D * 2);
    ushort* qbuf = (ushort*)alloc((size_t)N_NODES * D * 2);
    ushort* relp = (ushort*)alloc((size_t)N_REL * D * 2);
    int*   off   = (int*)alloc((size_t)(N_NODES + 1) * 4);
    float* rden  = (float*)alloc((size_t)N_NODES * H * 4);   // aliases cnt/cursor
    int*   cnt   = (int*)rden;
    int*   csr   = (int*)alloc((size_t)N_EDGES * 4);
    int*   bsum  = (int*)alloc((size_t)NB_SCAN * 4);
    int*   bpre  = (int*)alloc((size_t)NB_SCAN * 4);
    uint4* w1p   = (uint4*)alloc(8192 * 16);
    uint2* w2p   = (uint2*)alloc(16384 * 8);
    uint4* whp   = (uint4*)alloc(2048 * 16);
    uint4* wtp   = (uint4*)alloc(2048 * 16);
    uint4* wep   = (uint4*)alloc(2048 * 16);

    // weight packing (independent of everything else)
    prep_w1_kernel<<<32, 256, 0, stream>>>(W1, w1p);
    prep_w2_kernel<<<64, 256, 0, stream>>>(W2, w2p);
    prep_wp_kernel<<<8, 256, 0, stream>>>(Wh, whp);
    prep_wp_kernel<<<8, 256, 0, stream>>>(Wt, wtp);
    prep_wp_kernel<<<8, 256, 0, stream>>>(We, wep);

    // CSR build
    hipMemsetAsync(cnt, 0, (size_t)N_NODES * 4, stream);
    hist_kernel<<<1024, 256, 0, stream>>>(dst, cnt);
    scan1_kernel<<<NB_SCAN, 256, 0, stream>>>(cnt, off, bsum);
    scan2_kernel<<<1, 512, 0, stream>>>(bsum, bpre);
    scan3_kernel<<<NB_SCAN, 256, 0, stream>>>(off, bpre, cnt);
    fill_kernel<<<1024, 256, 0, stream>>>(src, dst, rid, cnt, csr);

    // projections
    ln_matmul_kernel<<<4, 256, 0, stream>>>(relf, g_rel, b_rel, Wr, relp, N_REL);
    proj_kernel<<<1563, 256, 0, stream>>>(ent, g_ent, b_ent, whp, wtp, wep, kbuf, qbuf, vbuf);

    attn_kernel<<<25000, 256, 0, stream>>>(kbuf, qbuf, relp, off, csr, ex, rden);

    diff_kernel<<<25000, 256, 0, stream>>>(vbuf, kbuf, vbuf, ex, rden, off, csr);
    diff_kernel<<<25000, 256, 0, stream>>>(kbuf, qbuf, vbuf, ex, rden, off, csr);
    diff_kernel<<<25000, 256, 0, stream>>>(qbuf, kbuf, vbuf, ex, rden, off, csr);
    diff_kernel<<<25000, 256, 0, stream>>>(kbuf, qbuf, vbuf, ex, rden, off, csr);

    ffn_mfma_kernel<<<1563, 256, 0, stream>>>(qbuf, ent, g_ff, b_ff, w1p, w2p, b1, b2, out);
}

// Round 6
// 889.024 us; speedup vs baseline: 2.0324x; 1.5065x over previous
//
#include <hip/hip_runtime.h>
#include <hip/hip_bf16.h>
#include <math.h>

#define N_NODES 100000
#define N_EDGES 1600000
#define N_REL   100
#define H       8
#define DH      16
#define D       128
#define DFF     512
#define ALPHA   0.1f

#define NB_SCAN ((N_NODES + 255) / 256)   // 391

typedef unsigned int uint32;

using f32x4 = __attribute__((ext_vector_type(4))) float;
using s16x8 = __attribute__((ext_vector_type(8))) short;
using s16x4 = __attribute__((ext_vector_type(4))) short;

__device__ __forceinline__ float bf2f(ushort u) {
    union { uint32 i; float f; } c; c.i = ((uint32)u) << 16; return c.f;
}
__device__ __forceinline__ ushort f2bf(float f) {
    union { uint32 i; float f; } c; c.f = f;
    uint32 i = c.i;
    uint32 r = (i + 0x7FFFu + ((i >> 16) & 1u)) >> 16;   // RNE
    return (ushort)r;
}
__device__ __forceinline__ uint32 pack2bf(float a, float b) {
    return (uint32)f2bf(a) | ((uint32)f2bf(b) << 16);
}
__device__ __forceinline__ float lo16(uint32 u) {
    union { uint32 i; float f; } c; c.i = u << 16; return c.f;
}
__device__ __forceinline__ float hi16(uint32 u) {
    union { uint32 i; float f; } c; c.i = u & 0xFFFF0000u; return c.f;
}

// ---------------- CSR construction ----------------

__global__ void hist_kernel(const int* __restrict__ dst, int* __restrict__ cnt) {
    int i = blockIdx.x * blockDim.x + threadIdx.x;
    int stride = gridDim.x * blockDim.x;
    for (; i < N_EDGES; i += stride)
        atomicAdd(&cnt[dst[i]], 1);
}

__global__ void scan1_kernel(const int* __restrict__ cnt, int* __restrict__ off,
                             int* __restrict__ bsum) {
    __shared__ int s[256];
    int t = threadIdx.x;
    int i = blockIdx.x * 256 + t;
    int v = (i < N_NODES) ? cnt[i] : 0;
    s[t] = v;
    __syncthreads();
    for (int d = 1; d < 256; d <<= 1) {
        int x = 0;
        if (t >= d) x = s[t - d];
        __syncthreads();
        s[t] += x;
        __syncthreads();
    }
    if (i < N_NODES) off[i] = s[t] - v;      // block-local exclusive
    if (t == 255) bsum[blockIdx.x] = s[255];
}

__global__ void scan2_kernel(const int* __restrict__ bsum, int* __restrict__ bpre) {
    __shared__ int s[512];
    int t = threadIdx.x;
    int v = (t < NB_SCAN) ? bsum[t] : 0;
    s[t] = v;
    __syncthreads();
    for (int d = 1; d < 512; d <<= 1) {
        int x = 0;
        if (t >= d) x = s[t - d];
        __syncthreads();
        s[t] += x;
        __syncthreads();
    }
    if (t < NB_SCAN) bpre[t] = s[t] - v;     // exclusive over block sums
}

__global__ void scan3_kernel(int* __restrict__ off, const int* __restrict__ bpre,
                             int* __restrict__ cursor) {
    int t = threadIdx.x;
    int i = blockIdx.x * 256 + t;
    if (i < N_NODES) {
        int val = off[i] + bpre[blockIdx.x];
        off[i] = val;
        cursor[i] = val;
    }
    if (blockIdx.x == 0 && t == 0) off[N_NODES] = N_EDGES;
}

// pack src (17 bits) | rid (7 bits) << 17
__global__ void fill_kernel(const int* __restrict__ src, const int* __restrict__ dst,
                            const int* __restrict__ rid, int* __restrict__ cursor,
                            int* __restrict__ csr) {
    int i = blockIdx.x * blockDim.x + threadIdx.x;
    int stride = gridDim.x * blockDim.x;
    for (; i < N_EDGES; i += stride) {
        int d = dst[i];
        int p = atomicAdd(&cursor[d], 1);
        csr[p] = src[i] | (rid[i] << 17);
    }
}

// ---------------- weight prep: pack into MFMA fragment layouts (bf16) ----------------
__global__ void prep_w1_kernel(const float* __restrict__ W1, uint4* __restrict__ w1p) {
    int idx = blockIdx.x * 256 + threadIdx.x;          // 8192 total
    int lane = idx & 63, kt = (idx >> 6) & 3, f = (idx >> 8) & 7, ch = idx >> 11;
    int ff = ch * 128 + f * 16 + (lane & 15);
    int k0 = kt * 32 + (lane >> 4) * 8;
    uint4 u;
    u.x = pack2bf(W1[(size_t)(k0 + 0) * DFF + ff], W1[(size_t)(k0 + 1) * DFF + ff]);
    u.y = pack2bf(W1[(size_t)(k0 + 2) * DFF + ff], W1[(size_t)(k0 + 3) * DFF + ff]);
    u.z = pack2bf(W1[(size_t)(k0 + 4) * DFF + ff], W1[(size_t)(k0 + 5) * DFF + ff]);
    u.w = pack2bf(W1[(size_t)(k0 + 6) * DFF + ff], W1[(size_t)(k0 + 7) * DFF + ff]);
    w1p[idx] = u;
}

__global__ void prep_w2_kernel(const float* __restrict__ W2, uint2* __restrict__ w2p) {
    int idx = blockIdx.x * 256 + threadIdx.x;          // 16384 total
    int lane = idx & 63, o = (idx >> 6) & 7, f = (idx >> 9) & 7, ch = idx >> 12;
    int col = o * 16 + (lane & 15);
    int k0 = ch * 128 + f * 16 + (lane >> 4) * 4;
    uint2 u;
    u.x = pack2bf(W2[(size_t)(k0 + 0) * D + col], W2[(size_t)(k0 + 1) * D + col]);
    u.y = pack2bf(W2[(size_t)(k0 + 2) * D + col], W2[(size_t)(k0 + 3) * D + col]);
    w2p[idx] = u;
}

__global__ void prep_wp_kernel(const float* __restrict__ W, uint4* __restrict__ wp) {
    int idx = blockIdx.x * 256 + threadIdx.x;          // 2048 total
    int lane = idx & 63, o = (idx >> 6) & 7, kt = idx >> 9;
    int col = o * 16 + (lane & 15);
    int k0 = kt * 32 + (lane >> 4) * 8;
    uint4 u;
    u.x = pack2bf(W[(size_t)(k0 + 0) * D + col], W[(size_t)(k0 + 1) * D + col]);
    u.y = pack2bf(W[(size_t)(k0 + 2) * D + col], W[(size_t)(k0 + 3) * D + col]);
    u.z = pack2bf(W[(size_t)(k0 + 4) * D + col], W[(size_t)(k0 + 5) * D + col]);
    u.w = pack2bf(W[(size_t)(k0 + 6) * D + col], W[(size_t)(k0 + 7) * D + col]);
    wp[idx] = u;
}

// ---------------- LN + matmul scalar (kept for rel, 100 rows) ----------------
__global__ void ln_matmul_kernel(const float* __restrict__ X, const float* __restrict__ g,
                                 const float* __restrict__ b, const float* __restrict__ W,
                                 ushort* __restrict__ outb, int nrows) {
    __shared__ float xn[32][D + 4];
    int t = threadIdx.x;
    int r0 = blockIdx.x * 32;
    {
        int lr = t >> 3, sub = t & 7;
        int row = r0 + lr;
        float x[16];
        float s = 0.f, ss = 0.f;
        if (row < nrows) {
            const float* Xp = X + (size_t)row * D + sub * 16;
            #pragma unroll
            for (int i = 0; i < 4; ++i) {
                float4 x4 = ((const float4*)Xp)[i];
                x[i*4+0] = x4.x; x[i*4+1] = x4.y; x[i*4+2] = x4.z; x[i*4+3] = x4.w;
            }
            #pragma unroll
            for (int i = 0; i < 16; ++i) { s += x[i]; ss += x[i]*x[i]; }
        } else {
            #pragma unroll
            for (int i = 0; i < 16; ++i) x[i] = 0.f;
        }
        s  += __shfl_xor(s, 1);  s  += __shfl_xor(s, 2);  s  += __shfl_xor(s, 4);
        ss += __shfl_xor(ss, 1); ss += __shfl_xor(ss, 2); ss += __shfl_xor(ss, 4);
        float m  = s * (1.f / D);
        float var = ss * (1.f / D) - m * m;
        float rs = rsqrtf(var + 1e-5f);
        #pragma unroll
        for (int i = 0; i < 16; ++i) {
            int idx = sub * 16 + i;
            float yv = (row < nrows) ? ((x[i] - m) * rs * g[idx] + b[idx]) : 0.f;
            xn[lr][idx] = yv;
        }
    }
    __syncthreads();

    int cg = t & 31;
    int rg = t >> 5;
    float4 acc[4];
    #pragma unroll
    for (int i = 0; i < 4; ++i) acc[i] = make_float4(0.f, 0.f, 0.f, 0.f);
    const float4* Wp = (const float4*)W + cg;
    #pragma unroll 8
    for (int d = 0; d < D; ++d) {
        float4 w = Wp[d * (D / 4)];
        #pragma unroll
        for (int i = 0; i < 4; ++i) {
            float xv = xn[rg * 4 + i][d];
            acc[i].x = fmaf(xv, w.x, acc[i].x);
            acc[i].y = fmaf(xv, w.y, acc[i].y);
            acc[i].z = fmaf(xv, w.z, acc[i].z);
            acc[i].w = fmaf(xv, w.w, acc[i].w);
        }
    }
    #pragma unroll
    for (int i = 0; i < 4; ++i) {
        int row = r0 + rg * 4 + i;
        if (row < nrows) {
            ushort4 u;
            u.x = f2bf(acc[i].x); u.y = f2bf(acc[i].y);
            u.z = f2bf(acc[i].z); u.w = f2bf(acc[i].w);
            *(ushort4*)(outb + (size_t)row * D + cg * 4) = u;
        }
    }
}

// ---------------- fused LN + 3 projections via MFMA ----------------
__global__ __launch_bounds__(256) void proj_kernel(
        const float* __restrict__ X, const float* __restrict__ g, const float* __restrict__ b,
        const uint4* __restrict__ whp, const uint4* __restrict__ wtp, const uint4* __restrict__ wep,
        ushort* __restrict__ kout, ushort* __restrict__ qout, ushort* __restrict__ vout) {
    int t = threadIdx.x, wid = t >> 6, l = t & 63, g4 = l >> 4, c = l & 15;
    int rbase = blockIdx.x * 64 + wid * 16;
    int row = rbase + c;
    int rowc = row < N_NODES ? row : N_NODES - 1;
    const float* Xp = X + (size_t)rowc * D;
    float x[32];
    float s = 0.f, ss = 0.f;
    #pragma unroll
    for (int kt = 0; kt < 4; ++kt) {
        float4 a0 = *(const float4*)(Xp + kt * 32 + g4 * 8);
        float4 a1 = *(const float4*)(Xp + kt * 32 + g4 * 8 + 4);
        x[kt*8+0] = a0.x; x[kt*8+1] = a0.y; x[kt*8+2] = a0.z; x[kt*8+3] = a0.w;
        x[kt*8+4] = a1.x; x[kt*8+5] = a1.y; x[kt*8+6] = a1.z; x[kt*8+7] = a1.w;
    }
    #pragma unroll
    for (int i = 0; i < 32; ++i) { s += x[i]; ss += x[i]*x[i]; }
    s  += __shfl_xor(s, 16);  s  += __shfl_xor(s, 32);
    ss += __shfl_xor(ss, 16); ss += __shfl_xor(ss, 32);
    float m  = s * (1.f / D);
    float var = ss * (1.f / D) - m * m;
    float rs = rsqrtf(var + 1e-5f);
    s16x8 yf[4];
    #pragma unroll
    for (int kt = 0; kt < 4; ++kt)
        #pragma unroll
        for (int j = 0; j < 8; ++j) {
            int idx = kt * 32 + g4 * 8 + j;
            yf[kt][j] = (short)f2bf((x[kt*8+j] - m) * rs * g[idx] + b[idx]);
        }

    const uint4* wps[3] = {whp, wtp, wep};
    ushort*      ops[3] = {kout, qout, vout};
    #pragma unroll
    for (int w = 0; w < 3; ++w) {
        f32x4 acc[8];
        #pragma unroll
        for (int o = 0; o < 8; ++o) acc[o] = (f32x4){0.f, 0.f, 0.f, 0.f};
        #pragma unroll
        for (int kt = 0; kt < 4; ++kt)
            #pragma unroll
            for (int o = 0; o < 8; ++o) {
                union { uint4 u; s16x8 v; } cv;
                cv.u = wps[w][(kt * 8 + o) * 64 + l];
                acc[o] = __builtin_amdgcn_mfma_f32_16x16x32_bf16(yf[kt], cv.v, acc[o], 0, 0, 0);
            }
        #pragma unroll
        for (int o = 0; o < 8; ++o)
            #pragma unroll
            for (int r = 0; r < 4; ++r) {
                int orow = rbase + g4 * 4 + r;
                if (orow < N_NODES)
                    ops[w][(size_t)orow * D + o * 16 + c] = f2bf(acc[o][r]);
            }
    }
}

// ---------------- edge attention: 8 edges x 8 heads per wave, no per-edge shuffles ----
__global__ void attn_kernel(const ushort* __restrict__ k, const ushort* __restrict__ q,
                            const ushort* __restrict__ relp, const int* __restrict__ off,
                            const int* __restrict__ csr,
                            ushort* __restrict__ ex, float* __restrict__ rdenom) {
    int n = blockIdx.x * 4 + (threadIdx.x >> 6);
    int lane = threadIdx.x & 63;
    int e = lane >> 3;          // edge slot within chunk
    int h = lane & 7;           // head
    int o0 = off[n], o1 = off[n + 1];
    int deg = o1 - o0;
    float scale = log1pf((float)deg) * 0.25f;   // log1p(in_deg)/sqrt(16)
    // preload q[n, h, :] with scale folded in
    const uint32* qrow = (const uint32*)q + (size_t)n * 64 + h * 8;
    float qf[16];
    #pragma unroll
    for (int i = 0; i < 8; ++i) {
        uint32 u = qrow[i];
        qf[2*i]   = lo16(u) * scale;
        qf[2*i+1] = hi16(u) * scale;
    }
    float dpart = 0.f;
    for (int j0 = o0; j0 < o1; j0 += 8) {
        int j = j0 + e;
        bool valid = j < o1;
        uint32 pk = (uint32)csr[valid ? j : o0];
        int s  = pk & 0x1FFFF;
        int ri = pk >> 17;
        const uint4* krow = (const uint4*)((const uint32*)k    + (size_t)s  * 64 + h * 8);
        const uint4* rrow = (const uint4*)((const uint32*)relp + (size_t)ri * 64 + h * 8);
        uint4 ka = krow[0], kb = krow[1];
        uint4 ra = rrow[0], rb = rrow[1];
        uint32 kw[8] = {ka.x, ka.y, ka.z, ka.w, kb.x, kb.y, kb.z, kb.w};
        uint32 rw[8] = {ra.x, ra.y, ra.z, ra.w, rb.x, rb.y, rb.z, rb.w};
        float p = 0.f;
        #pragma unroll
        for (int i = 0; i < 8; ++i) {
            p = fmaf(lo16(kw[i]) * lo16(rw[i]), qf[2*i],   p);
            p = fmaf(hi16(kw[i]) * hi16(rw[i]), qf[2*i+1], p);
        }
        float ev = valid ? __expf(p) : 0.f;
        dpart += ev;
        if (valid) ex[(size_t)j * H + h] = f2bf(ev);
    }
    dpart += __shfl_xor(dpart, 8);
    dpart += __shfl_xor(dpart, 16);
    dpart += __shfl_xor(dpart, 32);
    if (lane < 8) rdenom[n * H + lane] = (deg > 0) ? (1.f - ALPHA) / dpart : 0.f;
}

// ---------------- one diffusion hop (bf16 feat), 4-edge unrolled ----------------
__global__ void diff_kernel(const ushort* __restrict__ fin, ushort* __restrict__ fout,
                            const ushort* __restrict__ f0, const ushort* __restrict__ ex,
                            const float* __restrict__ rdenom, const int* __restrict__ off,
                            const int* __restrict__ csr) {
    int n = blockIdx.x * 4 + (threadIdx.x >> 6);
    int lane = threadIdx.x & 63;
    int hg = lane >> 3;
    int o0 = off[n], o1 = off[n + 1];
    const uint32* fin32 = (const uint32*)fin;
    float ax = 0.f, ay = 0.f;
    int j = o0;
    for (; j + 4 <= o1; j += 4) {
        int s0 = csr[j]     & 0x1FFFF;
        int s1 = csr[j + 1] & 0x1FFFF;
        int s2 = csr[j + 2] & 0x1FFFF;
        int s3 = csr[j + 3] & 0x1FFFF;
        float a0 = bf2f(ex[(size_t)(j + 0) * H + hg]);
        float a1 = bf2f(ex[(size_t)(j + 1) * H + hg]);
        float a2 = bf2f(ex[(size_t)(j + 2) * H + hg]);
        float a3 = bf2f(ex[(size_t)(j + 3) * H + hg]);
        uint32 f0w = fin32[(size_t)s0 * 64 + lane];
        uint32 f1w = fin32[(size_t)s1 * 64 + lane];
        uint32 f2w = fin32[(size_t)s2 * 64 + lane];
        uint32 f3w = fin32[(size_t)s3 * 64 + lane];
        ax = fmaf(a0, lo16(f0w), ax); ay = fmaf(a0, hi16(f0w), ay);
        ax = fmaf(a1, lo16(f1w), ax); ay = fmaf(a1, hi16(f1w), ay);
        ax = fmaf(a2, lo16(f2w), ax); ay = fmaf(a2, hi16(f2w), ay);
        ax = fmaf(a3, lo16(f3w), ax); ay = fmaf(a3, hi16(f3w), ay);
    }
    for (; j < o1; ++j) {
        int s = csr[j] & 0x1FFFF;
        float a = bf2f(ex[(size_t)j * H + hg]);
        uint32 fw = fin32[(size_t)s * 64 + lane];
        ax = fmaf(a, lo16(fw), ax);
        ay = fmaf(a, hi16(fw), ay);
    }
    float rd = rdenom[n * H + hg];                 // (1-alpha)/denom, 0 if deg==0
    uint32 f0b = ((const uint32*)f0)[(size_t)n * 64 + lane];
    float ox = fmaf(rd, ax, ALPHA * lo16(f0b));
    float oy = fmaf(rd, ay, ALPHA * hi16(f0b));
    ((uint32*)fout)[(size_t)n * 64 + lane] = pack2bf(ox, oy);
}

// ---------------- fused residual + LN + FFN + residual via MFMA ----------------
__global__ __launch_bounds__(256) void ffn_mfma_kernel(
        const ushort* __restrict__ featb, const float* __restrict__ ent,
        const float* __restrict__ gff, const float* __restrict__ bff,
        const uint4* __restrict__ w1p, const uint2* __restrict__ w2p,
        const float* __restrict__ b1, const float* __restrict__ b2,
        float* __restrict__ out) {
    int t = threadIdx.x, wid = t >> 6, l = t & 63, g4 = l >> 4, c = l & 15;
    int rbase = blockIdx.x * 64 + wid * 16;
    int row = rbase + c;
    int rowc = row < N_NODES ? row : N_NODES - 1;
    const ushort* fp = featb + (size_t)rowc * D;
    const float*  ep = ent   + (size_t)rowc * D;
    float x[32];
    float s = 0.f, ss = 0.f;
    #pragma unroll
    for (int kt = 0; kt < 4; ++kt) {
        uint4  fu = *(const uint4*)(fp + kt * 32 + g4 * 8);
        float4 e0 = *(const float4*)(ep + kt * 32 + g4 * 8);
        float4 e1 = *(const float4*)(ep + kt * 32 + g4 * 8 + 4);
        uint32 fw[4] = {fu.x, fu.y, fu.z, fu.w};
        float  ev[8] = {e0.x, e0.y, e0.z, e0.w, e1.x, e1.y, e1.z, e1.w};
        #pragma unroll
        for (int p = 0; p < 4; ++p) {
            x[kt*8 + 2*p]   = lo16(fw[p]) + ev[2*p];
            x[kt*8 + 2*p+1] = hi16(fw[p]) + ev[2*p+1];
        }
    }
    #pragma unroll
    for (int i = 0; i < 32; ++i) { s += x[i]; ss += x[i]*x[i]; }
    s  += __shfl_xor(s, 16);  s  += __shfl_xor(s, 32);
    ss += __shfl_xor(ss, 16); ss += __shfl_xor(ss, 32);
    float m  = s * (1.f / D);
    float var = ss * (1.f / D) - m * m;
    float rs = rsqrtf(var + 1e-5f);
    s16x8 yf[4];
    #pragma unroll
    for (int kt = 0; kt < 4; ++kt)
        #pragma unroll
        for (int j = 0; j < 8; ++j) {
            int idx = kt * 32 + g4 * 8 + j;
            yf[kt][j] = (short)f2bf((x[kt*8+j] - m) * rs * gff[idx] + bff[idx]);
        }

    f32x4 oacc[8];
    #pragma unroll
    for (int o = 0; o < 8; ++o) oacc[o] = (f32x4){0.f, 0.f, 0.f, 0.f};
    const f32x4* b1v4 = (const f32x4*)b1;

    #pragma unroll
    for (int ch = 0; ch < 4; ++ch) {
        f32x4 hacc[8];
        #pragma unroll
        for (int f = 0; f < 8; ++f) hacc[f] = b1v4[ch * 32 + f * 4 + g4];
        #pragma unroll
        for (int f = 0; f < 8; ++f)
            #pragma unroll
            for (int kt = 0; kt < 4; ++kt) {
                union { uint4 u; s16x8 v; } cv;
                cv.u = w1p[((ch * 8 + f) * 4 + kt) * 64 + l];
                hacc[f] = __builtin_amdgcn_mfma_f32_16x16x32_bf16(cv.v, yf[kt], hacc[f], 0, 0, 0);
            }
        s16x4 a2[8];
        #pragma unroll
        for (int f = 0; f < 8; ++f)
            #pragma unroll
            for (int r = 0; r < 4; ++r)
                a2[f][r] = (short)f2bf(fmaxf(hacc[f][r], 0.f));
        #pragma unroll
        for (int o = 0; o < 8; ++o)
            #pragma unroll
            for (int f = 0; f < 8; ++f) {
                union { uint2 u; s16x4 v; } cw;
                cw.u = w2p[((ch * 8 + f) * 8 + o) * 64 + l];
                oacc[o] = __builtin_amdgcn_mfma_f32_16x16x16bf16_1k(a2[f], cw.v, oacc[o], 0, 0, 0);
            }
    }

    #pragma unroll
    for (int o = 0; o < 8; ++o) {
        int col = o * 16 + c;
        float b2v = b2[col];
        #pragma unroll
        for (int r = 0; r < 4; ++r) {
            int orow = rbase + g4 * 4 + r;
            if (orow < N_NODES) {
                float res = bf2f(featb[(size_t)orow * D + col]) + ent[(size_t)orow * D + col];
                out[(size_t)orow * D + col] = oacc[o][r] + b2v + res;
            }
        }
    }
}

extern "C" void kernel_launch(void* const* d_in, const int* in_sizes, int n_in,
                              void* d_out, int out_size, void* d_ws, size_t ws_size,
                              hipStream_t stream) {
    const float* ent   = (const float*)d_in[0];
    const float* relf  = (const float*)d_in[1];
    const float* Wh    = (const float*)d_in[2];
    const float* Wt    = (const float*)d_in[3];
    const float* We    = (const float*)d_in[4];
    const float* Wr    = (const float*)d_in[5];
    const float* g_ent = (const float*)d_in[6];
    const float* b_ent = (const float*)d_in[7];
    const float* g_rel = (const float*)d_in[8];
    const float* b_rel = (const float*)d_in[9];
    const float* g_ff  = (const float*)d_in[10];
    const float* b_ff  = (const float*)d_in[11];
    const float* W1    = (const float*)d_in[12];
    const float* b1    = (const float*)d_in[13];
    const float* W2    = (const float*)d_in[14];
    const float* b2    = (const float*)d_in[15];
    const int*   src   = (const int*)d_in[16];
    const int*   dst   = (const int*)d_in[17];
    const int*   rid   = (const int*)d_in[18];
    float* out = (float*)d_out;

    // ---- d_out doubles as scratch until the final ffn kernel ----
    ushort* ex   = (ushort*)d_out;                                    // 25.6 MB
    ushort* vbuf = (ushort*)((char*)d_out + (size_t)N_EDGES * H * 2); // 25.6 MB

    // ---- workspace (~62 MB) ----
    char* w = (char*)d_ws;
    auto alloc = [&](size_t bytes) { char* p = w; w += (bytes + 255) & ~(size_t)255; return p; };
    ushort* kbuf = (ushort*)alloc((size_t)N_NODES * D * 2);
    ushort* qbuf = (ushort*)alloc((size_t)N_NODES * D * 2);
    ushort* relp = (ushort*)alloc((size_t)N_REL * D * 2);
    int*   off   = (int*)alloc((size_t)(N_NODES + 1) * 4);
    float* rden  = (float*)alloc((size_t)N_NODES * H * 4);   // aliases cnt/cursor
    int*   cnt   = (int*)rden;
    int*   csr   = (int*)alloc((size_t)N_EDGES * 4);
    int*   bsum  = (int*)alloc((size_t)NB_SCAN * 4);
    int*   bpre  = (int*)alloc((size_t)NB_SCAN * 4);
    uint4* w1p   = (uint4*)alloc(8192 * 16);
    uint2* w2p   = (uint2*)alloc(16384 * 8);
    uint4* whp   = (uint4*)alloc(2048 * 16);
    uint4* wtp   = (uint4*)alloc(2048 * 16);
    uint4* wep   = (uint4*)alloc(2048 * 16);

    // weight packing (independent of everything else)
    prep_w1_kernel<<<32, 256, 0, stream>>>(W1, w1p);
    prep_w2_kernel<<<64, 256, 0, stream>>>(W2, w2p);
    prep_wp_kernel<<<8, 256, 0, stream>>>(Wh, whp);
    prep_wp_kernel<<<8, 256, 0, stream>>>(Wt, wtp);
    prep_wp_kernel<<<8, 256, 0, stream>>>(We, wep);

    // CSR build
    hipMemsetAsync(cnt, 0, (size_t)N_NODES * 4, stream);
    hist_kernel<<<1024, 256, 0, stream>>>(dst, cnt);
    scan1_kernel<<<NB_SCAN, 256, 0, stream>>>(cnt, off, bsum);
    scan2_kernel<<<1, 512, 0, stream>>>(bsum, bpre);
    scan3_kernel<<<NB_SCAN, 256, 0, stream>>>(off, bpre, cnt);
    fill_kernel<<<1024, 256, 0, stream>>>(src, dst, rid, cnt, csr);

    // projections
    ln_matmul_kernel<<<4, 256, 0, stream>>>(relf, g_rel, b_rel, Wr, relp, N_REL);
    proj_kernel<<<1563, 256, 0, stream>>>(ent, g_ent, b_ent, whp, wtp, wep, kbuf, qbuf, vbuf);

    attn_kernel<<<25000, 256, 0, stream>>>(kbuf, qbuf, relp, off, csr, ex, rden);

    diff_kernel<<<25000, 256, 0, stream>>>(vbuf, kbuf, vbuf, ex, rden, off, csr);
    diff_kernel<<<25000, 256, 0, stream>>>(kbuf, qbuf, vbuf, ex, rden, off, csr);
    diff_kernel<<<25000, 256, 0, stream>>>(qbuf, kbuf, vbuf, ex, rden, off, csr);
    diff_kernel<<<25000, 256, 0, stream>>>(kbuf, qbuf, vbuf, ex, rden, off, csr);

    ffn_mfma_kernel<<<1563, 256, 0, stream>>>(qbuf, ent, g_ff, b_ff, w1p, w2p, b1, b2, out);
}